// Round 1
// baseline (8602.120 us; speedup 1.0000x reference)
//
#include <hip/hip_runtime.h>
#include <stdint.h>

// NpiLstm: T=512, B=128, H=1024, IN=64 (63 x-features + 1 feedback)
// Feedback folded into recurrent weights: W_hh' = W_hh + w_fb (x) W_lin.
// Persistent 256-block cooperative kernel, 1 device barrier per step.

typedef short short8 __attribute__((ext_vector_type(8)));
typedef float float4v __attribute__((ext_vector_type(4)));
typedef int int4v __attribute__((ext_vector_type(4)));

#define KP 1152      // padded K: 63 x | 1 zero | 1024 h | 64 zero-pad
#define NBLK 256

__device__ __forceinline__ unsigned short f2bf(float f) {
  unsigned int u = __float_as_uint(f);
  u += 0x7fffu + ((u >> 16) & 1u);   // RNE
  return (unsigned short)(u >> 16);
}
__device__ __forceinline__ float sigm(float x) { return 1.0f / (1.0f + __expf(-x)); }
__device__ __forceinline__ float tanh_f(float x) {
  float ax = fabsf(x);
  float e = __expf(-2.0f * ax);
  float r = (1.0f - e) / (1.0f + e);
  return x < 0.0f ? -r : r;
}

// ---- build W_cat [4096][1152] bf16 and biases b1/b2 [4096] f32 ----
__global__ void prep_w(const float* __restrict__ W_ih, const float* __restrict__ W_hh,
                       const float* __restrict__ W_lin, const float* __restrict__ b_ih,
                       const float* __restrict__ b_hh, const float* __restrict__ b_lin,
                       unsigned short* __restrict__ Wcat, float* __restrict__ b1,
                       float* __restrict__ b2) {
  int idx = blockIdx.x * 256 + threadIdx.x;
  if (idx < 4096 * KP) {
    int j = idx / KP;
    int k = idx - j * KP;
    float v = 0.0f;
    if (k < 63) v = W_ih[j * 64 + k];
    else if (k >= 64 && k < 1088) {
      int kk = k - 64;
      v = W_hh[j * 1024 + kk] + W_ih[j * 64 + 63] * W_lin[kk];
    }
    Wcat[idx] = f2bf(v);
  }
  if (idx < 4096) {
    float wfb = W_ih[idx * 64 + 63];
    float base = b_ih[idx] + b_hh[idx];
    b1[idx] = base + 1e-9f * wfb;      // step 1: feedback value is INIT_OUT
    b2[idx] = base + b_lin[0] * wfb;   // steps >=2: folded b_lin feedback
  }
}

// ---- x -> bf16, padded to 64 channels ----
__global__ void prep_x(const float* __restrict__ x, unsigned short* __restrict__ xbf) {
  int idx = blockIdx.x * 256 + threadIdx.x;   // < 512*128*64 exactly
  int c = idx & 63;
  int bi = idx >> 6;
  unsigned short v = 0;
  if (c < 63) v = f2bf(x[bi * 63 + c]);
  xbf[idx] = v;
}

// ---- zero h0 buffer + barrier state ----
__global__ void initk(unsigned short* __restrict__ Hbuf, int* __restrict__ bar) {
  int idx = blockIdx.x * 256 + threadIdx.x;
  if (idx < 65536) reinterpret_cast<unsigned int*>(Hbuf)[idx] = 0u;
  if (idx < 16) bar[idx] = 0;
}

// ---- persistent recurrent kernel: 256 blocks (1/CU), 256 threads ----
// block (bg = bid>>6 in [0,4), cg = bid&63 in [0,64)) owns h-tile [bg*32..+32) x [cg*16..+16)
// wave wv in [0,4) covers K-tiles [9*wv, 9*wv+9) for all 4 gates (K-split + LDS reduce)
__global__ __launch_bounds__(256, 1) void lstm_rec(
    const unsigned short* __restrict__ Wcat, const unsigned short* __restrict__ xbf,
    const float* __restrict__ b1, const float* __restrict__ b2,
    const float* __restrict__ Wlin, unsigned short* __restrict__ Hbuf,
    float* __restrict__ outp, int* __restrict__ bar) {
  const int tid = threadIdx.x;
  const int bid = blockIdx.x;
  const int bg = bid >> 6;
  const int cg = bid & 63;
  const int wv = tid >> 6;
  const int ln = tid & 63;
  const int lr = ln & 15;   // fragment row/col within 16
  const int lq = ln >> 4;   // k-quarter

  __shared__ __align__(16) char zs[32 * 2304];          // Z: 32 rows x 1152 bf16, XOR-swizzled
  __shared__ float pbuf[4][4][32][17];                  // per-wave gate partials (padded)

  // --- load B fragments (weights) into registers, once ---
  short8 bf[4][9];
#pragma unroll
  for (int g = 0; g < 4; ++g) {
    const unsigned short* wrow = Wcat + (size_t)(g * 1024 + cg * 16 + lr) * KP;
#pragma unroll
    for (int j = 0; j < 9; ++j) {
      int k = (wv * 9 + j) * 32 + lq * 8;
      bf[g][j] = *reinterpret_cast<const short8*>(wrow + k);
    }
  }

  // pointwise-phase mapping: thread -> (row pr, cols pc, pc+1)
  const int pr = tid >> 3;
  const int pc = (tid & 7) * 2;
  float bias2[4][2];
#pragma unroll
  for (int g = 0; g < 4; ++g) {
    int j0 = g * 1024 + cg * 16 + pc;
    bias2[g][0] = b2[j0];
    bias2[g][1] = b2[j0 + 1];
  }
  float wl0 = Wlin[cg * 16 + pc];
  float wl1 = Wlin[cg * 16 + pc + 1];
  float cst0 = 0.0f, cst1 = 0.0f;   // cell state lives in registers across all steps

  for (int t = 1; t < 512; ++t) {
    const unsigned short* hsrc = Hbuf + ((t - 1) & 1) * 131072;
    const unsigned short* xsrc = xbf + (size_t)t * 8192;
    // --- stage Z = [x_t | 0 | h_{t-1} | 0] into swizzled LDS (18 chunks/thread) ---
#pragma unroll
    for (int half = 0; half < 2; ++half) {
      int4v tmp[9];
#pragma unroll
      for (int s = 0; s < 9; ++s) {
        int ci = (half * 9 + s) * 256 + tid;   // < 4608 = 32 rows * 144 chunks
        int row = ci / 144;
        int col = ci - row * 144;
        int4v v = {0, 0, 0, 0};
        if (col < 8)
          v = *reinterpret_cast<const int4v*>(xsrc + (size_t)(bg * 32 + row) * 64 + col * 8);
        else if (col < 136)
          v = *reinterpret_cast<const int4v*>(hsrc + (size_t)(bg * 32 + row) * 1024 + (col - 8) * 8);
        tmp[s] = v;
      }
#pragma unroll
      for (int s = 0; s < 9; ++s) {
        int ci = (half * 9 + s) * 256 + tid;
        int row = ci / 144;
        int col = ci - row * 144;
        *reinterpret_cast<int4v*>(zs + row * 2304 + ((col * 16) ^ ((row & 7) << 4))) = tmp[s];
      }
    }
    __syncthreads();

    // --- MFMA K-loop: 4 gates x 2 M-tiles, 9 K-tiles per wave ---
    float4v acc[4][2];
#pragma unroll
    for (int g = 0; g < 4; ++g) {
      acc[g][0] = (float4v){0.f, 0.f, 0.f, 0.f};
      acc[g][1] = (float4v){0.f, 0.f, 0.f, 0.f};
    }
#pragma unroll
    for (int j = 0; j < 9; ++j) {
      int bc = (wv * 9 + j) * 64 + lq * 16;
      short8 a0 = *reinterpret_cast<const short8*>(zs + lr * 2304 + (bc ^ ((lr & 7) << 4)));
      short8 a1 = *reinterpret_cast<const short8*>(zs + (16 + lr) * 2304 + (bc ^ ((lr & 7) << 4)));
#pragma unroll
      for (int g = 0; g < 4; ++g) {
        acc[g][0] = __builtin_amdgcn_mfma_f32_16x16x32_bf16(a0, bf[g][j], acc[g][0], 0, 0, 0);
        acc[g][1] = __builtin_amdgcn_mfma_f32_16x16x32_bf16(a1, bf[g][j], acc[g][1], 0, 0, 0);
      }
    }
    // write per-wave partials (C/D layout: col = ln&15, row = (ln>>4)*4 + r)
#pragma unroll
    for (int g = 0; g < 4; ++g)
#pragma unroll
      for (int m = 0; m < 2; ++m)
#pragma unroll
        for (int r = 0; r < 4; ++r)
          pbuf[wv][g][m * 16 + lq * 4 + r][lr] = acc[g][m][r];
    __syncthreads();

    // --- pointwise: reduce 4 wave-partials, gates -> c,h ---
    float lb[4][2];
    if (t == 1) {
#pragma unroll
      for (int g = 0; g < 4; ++g) {
        int j0 = g * 1024 + cg * 16 + pc;
        lb[g][0] = b1[j0];
        lb[g][1] = b1[j0 + 1];
      }
    } else {
#pragma unroll
      for (int g = 0; g < 4; ++g) { lb[g][0] = bias2[g][0]; lb[g][1] = bias2[g][1]; }
    }
    float ga0[4], ga1[4];
#pragma unroll
    for (int g = 0; g < 4; ++g) {
      ga0[g] = pbuf[0][g][pr][pc] + pbuf[1][g][pr][pc] + pbuf[2][g][pr][pc] + pbuf[3][g][pr][pc] + lb[g][0];
      ga1[g] = pbuf[0][g][pr][pc + 1] + pbuf[1][g][pr][pc + 1] + pbuf[2][g][pr][pc + 1] + pbuf[3][g][pr][pc + 1] + lb[g][1];
    }
    float i0 = sigm(ga0[0]), f0 = sigm(ga0[1]), gg0 = tanh_f(ga0[2]), o0 = sigm(ga0[3]);
    float i1 = sigm(ga1[0]), f1 = sigm(ga1[1]), gg1 = tanh_f(ga1[2]), o1 = sigm(ga1[3]);
    cst0 = f0 * cst0 + i0 * gg0;
    cst1 = f1 * cst1 + i1 * gg1;
    float h0 = o0 * tanh_f(cst0);
    float h1 = o1 * tanh_f(cst1);
    unsigned int packed = (unsigned int)f2bf(h0) | ((unsigned int)f2bf(h1) << 16);
    *reinterpret_cast<unsigned int*>(Hbuf + (t & 1) * 131072 +
                                     (size_t)(bg * 32 + pr) * 1024 + cg * 16 + pc) = packed;
    // W_lin partial for this block's 16 columns (fp32 h, deterministic)
    float p = h0 * wl0 + h1 * wl1;
    p += __shfl_xor(p, 1);
    p += __shfl_xor(p, 2);
    p += __shfl_xor(p, 4);
    if ((tid & 7) == 0) outp[((size_t)t * 128 + bg * 32 + pr) * 64 + cg] = p;

    // --- device-wide barrier (sense = step t) ---
    __syncthreads();   // compiler drains vmcnt before s_barrier -> stores are in L2
    if (tid == 0) {
      int n = __hip_atomic_fetch_add(&bar[0], 1, __ATOMIC_ACQ_REL, __HIP_MEMORY_SCOPE_AGENT);
      if (n == NBLK - 1) {
        __hip_atomic_store(&bar[0], 0, __ATOMIC_RELAXED, __HIP_MEMORY_SCOPE_AGENT);
        __hip_atomic_store(&bar[1], t, __ATOMIC_RELEASE, __HIP_MEMORY_SCOPE_AGENT);
      } else {
        int guard = 0;
        while (__hip_atomic_load(&bar[1], __ATOMIC_RELAXED, __HIP_MEMORY_SCOPE_AGENT) < t) {
          __builtin_amdgcn_s_sleep(4);
          if (++guard > (1 << 22)) break;   // hang-safety valve
        }
        (void)__hip_atomic_load(&bar[1], __ATOMIC_ACQUIRE, __HIP_MEMORY_SCOPE_AGENT);
      }
    }
    __syncthreads();
  }
}

// ---- out[t][b] = b_lin + sum_cg outp[t][b][cg]; row 0 = INIT_OUT ----
__global__ void finalize(const float* __restrict__ outp, const float* __restrict__ b_lin,
                         float* __restrict__ out) {
  int row = blockIdx.x * 4 + (threadIdx.x >> 6);
  int lane = threadIdx.x & 63;
  if (row < 128) {
    if (lane == 0) out[row] = 1e-9f;
    return;
  }
  float v = outp[(size_t)row * 64 + lane];
  v += __shfl_down(v, 32);
  v += __shfl_down(v, 16);
  v += __shfl_down(v, 8);
  v += __shfl_down(v, 4);
  v += __shfl_down(v, 2);
  v += __shfl_down(v, 1);
  if (lane == 0) out[row] = v + b_lin[0];
}

extern "C" void kernel_launch(void* const* d_in, const int* in_sizes, int n_in,
                              void* d_out, int out_size, void* d_ws, size_t ws_size,
                              hipStream_t stream) {
  const float* x = (const float*)d_in[0];
  const float* W_ih = (const float*)d_in[1];
  const float* W_hh = (const float*)d_in[2];
  const float* b_ih = (const float*)d_in[3];
  const float* b_hh = (const float*)d_in[4];
  const float* W_lin = (const float*)d_in[5];
  const float* b_lin = (const float*)d_in[6];
  float* out = (float*)d_out;

  char* ws = (char*)d_ws;
  const size_t WS_WCAT = 0;                  // 4096*1152*2   = 9437184
  const size_t WS_XBF  = 9437184;            // 512*128*64*2  = 8388608
  const size_t WS_B1   = 17825792;           // 16384
  const size_t WS_B2   = 17842176;           // 16384
  const size_t WS_H    = 17858560;           // 2*128*1024*2  = 524288
  const size_t WS_OUTP = 18382848;           // 512*128*64*4  = 16777216
  const size_t WS_BAR  = 35160064;           // 64
  if (ws_size < WS_BAR + 64) return;         // insufficient scratch -> fail loudly

  unsigned short* Wcat = (unsigned short*)(ws + WS_WCAT);
  unsigned short* xbf = (unsigned short*)(ws + WS_XBF);
  float* b1 = (float*)(ws + WS_B1);
  float* b2 = (float*)(ws + WS_B2);
  unsigned short* Hbuf = (unsigned short*)(ws + WS_H);
  float* outp = (float*)(ws + WS_OUTP);
  int* bar = (int*)(ws + WS_BAR);

  prep_w<<<18432, 256, 0, stream>>>(W_ih, W_hh, W_lin, b_ih, b_hh, b_lin, Wcat, b1, b2);
  prep_x<<<16384, 256, 0, stream>>>(x, xbf);
  initk<<<256, 256, 0, stream>>>(Hbuf, bar);
  lstm_rec<<<256, 256, 0, stream>>>(Wcat, xbf, b1, b2, W_lin, Hbuf, outp, bar);
  finalize<<<16384, 256, 0, stream>>>(outp, b_lin, out);
}

// Round 2
// 3011.117 us; speedup vs baseline: 2.8568x; 2.8568x over previous
//
#include <hip/hip_runtime.h>
#include <stdint.h>

// NpiLstm: T=512, B=128, H=1024, IN=64 (63 x-features + 1 feedback)
// Feedback folded into recurrent weights: W_hh' = W_hh + w_fb (x) W_lin.
// Persistent 256-block kernel; 4 independent batch-groups of 64 blocks;
// flag-array barrier (no atomic contention, no cache invalidates);
// h exchanged via coherence-point (AGENT-scope) atomics.

typedef short short8 __attribute__((ext_vector_type(8)));
typedef float float4v __attribute__((ext_vector_type(4)));
typedef int int4v __attribute__((ext_vector_type(4)));
typedef unsigned long long u64;

#define KP 1152      // padded K: 63 x | 1 zero | 1024 h | 64 zero-pad

__device__ __forceinline__ unsigned short f2bf(float f) {
  unsigned int u = __float_as_uint(f);
  u += 0x7fffu + ((u >> 16) & 1u);   // RNE
  return (unsigned short)(u >> 16);
}
__device__ __forceinline__ float sigm(float x) { return 1.0f / (1.0f + __expf(-x)); }
__device__ __forceinline__ float tanh_f(float x) {
  float ax = fabsf(x);
  float e = __expf(-2.0f * ax);
  float r = (1.0f - e) / (1.0f + e);
  return x < 0.0f ? -r : r;
}

// ---- build W_cat [4096][1152] bf16 and biases b1/b2 [4096] f32 ----
__global__ void prep_w(const float* __restrict__ W_ih, const float* __restrict__ W_hh,
                       const float* __restrict__ W_lin, const float* __restrict__ b_ih,
                       const float* __restrict__ b_hh, const float* __restrict__ b_lin,
                       unsigned short* __restrict__ Wcat, float* __restrict__ b1,
                       float* __restrict__ b2) {
  int idx = blockIdx.x * 256 + threadIdx.x;
  if (idx < 4096 * KP) {
    int j = idx / KP;
    int k = idx - j * KP;
    float v = 0.0f;
    if (k < 63) v = W_ih[j * 64 + k];
    else if (k >= 64 && k < 1088) {
      int kk = k - 64;
      v = W_hh[j * 1024 + kk] + W_ih[j * 64 + 63] * W_lin[kk];
    }
    Wcat[idx] = f2bf(v);
  }
  if (idx < 4096) {
    float wfb = W_ih[idx * 64 + 63];
    float base = b_ih[idx] + b_hh[idx];
    b1[idx] = base + 1e-9f * wfb;      // step 1: feedback value is INIT_OUT
    b2[idx] = base + b_lin[0] * wfb;   // steps >=2: folded b_lin feedback
  }
}

// ---- x -> bf16, padded to 64 channels ----
__global__ void prep_x(const float* __restrict__ x, unsigned short* __restrict__ xbf) {
  int idx = blockIdx.x * 256 + threadIdx.x;   // < 512*128*64 exactly
  int c = idx & 63;
  int bi = idx >> 6;
  unsigned short v = 0;
  if (c < 63) v = f2bf(x[bi * 63 + c]);
  xbf[idx] = v;
}

// ---- zero h0 slice + per-block flags ----
__global__ void initk(unsigned short* __restrict__ Hbuf, int* __restrict__ flags) {
  int idx = blockIdx.x * 256 + threadIdx.x;
  if (idx < 65536) reinterpret_cast<unsigned int*>(Hbuf)[idx] = 0u;
  if (idx < 256) flags[idx] = 0;
}

// ---- persistent recurrent kernel: 256 blocks (1/CU), 256 threads ----
// group = bg (bid>>6): 64 blocks, independent chain over 32 batch rows.
// block owns h-tile [bg*32..+32) x [cg*16..+16); wave wv: K-tiles [9wv,9wv+9)
__global__ __launch_bounds__(256, 1) void lstm_rec(
    const unsigned short* __restrict__ Wcat, const unsigned short* __restrict__ xbf,
    const float* __restrict__ b1, const float* __restrict__ b2,
    const float* __restrict__ Wlin, unsigned short* __restrict__ Hbuf,
    float* __restrict__ outp, int* __restrict__ flags) {
  const int tid = threadIdx.x;
  const int bid = blockIdx.x;
  const int bg = bid >> 6;
  const int cg = bid & 63;
  const int wv = tid >> 6;
  const int ln = tid & 63;
  const int lr = ln & 15;   // fragment row/col within 16
  const int lq = ln >> 4;   // k-quarter

  __shared__ __align__(16) char zs[32 * 2304];          // Z: 32 rows x 1152 bf16, XOR-swizzled
  __shared__ __align__(16) float pbuf2[4][4][16][36];   // [wave][gate][col][row+pad]

  // --- load B fragments (weights) into registers, once ---
  short8 bf[4][9];
#pragma unroll
  for (int g = 0; g < 4; ++g) {
    const unsigned short* wrow = Wcat + (size_t)(g * 1024 + cg * 16 + lr) * KP;
#pragma unroll
    for (int j = 0; j < 9; ++j) {
      int k = (wv * 9 + j) * 32 + lq * 8;
      bf[g][j] = *reinterpret_cast<const short8*>(wrow + k);
    }
  }

  // zero the K-pad chunks (cols 136..143) once; never rewritten
  {
    int row = tid >> 3, c = 136 + (tid & 7);
    int4v z = {0, 0, 0, 0};
    *reinterpret_cast<int4v*>(zs + row * 2304 + ((c * 16) ^ ((row & 7) << 4))) = z;
  }

  // pointwise-phase mapping: thread -> (row pr, cols pc, pc+1)
  const int pr = tid >> 3;
  const int pc = (tid & 7) * 2;
  float bias2[4][2];
#pragma unroll
  for (int g = 0; g < 4; ++g) {
    int j0 = g * 1024 + cg * 16 + pc;
    bias2[g][0] = b2[j0];
    bias2[g][1] = b2[j0 + 1];
  }
  float wl0 = Wlin[cg * 16 + pc];
  float wl1 = Wlin[cg * 16 + pc + 1];
  float cst0 = 0.0f, cst1 = 0.0f;   // cell state lives in registers across all steps

  for (int t = 1; t < 512; ++t) {
    // --- group barrier: wait until all 64 group blocks finished step t-1 ---
    if (t > 1 && tid < 64) {
      int guard = 0;
      for (;;) {
        int v = __hip_atomic_load(flags + (bid & ~63) + tid, __ATOMIC_RELAXED,
                                  __HIP_MEMORY_SCOPE_AGENT);
        if (__all(v >= t - 1)) break;
        __builtin_amdgcn_s_sleep(1);
        if (++guard > (1 << 18)) break;   // hang-safety valve
      }
    }
    __syncthreads();

    // --- stage Z = [x_t | 0 | h_{t-1}] into swizzled LDS ---
    const u64* Hu = reinterpret_cast<const u64*>(Hbuf) + ((t - 1) & 1) * 32768 +
                    (size_t)bg * 32 * 256;
    const unsigned short* xsrc = xbf + (size_t)t * 8192 + (size_t)bg * 32 * 64;
    int xr = tid >> 3, xc = tid & 7;
    int4v xv = *reinterpret_cast<const int4v*>(xsrc + xr * 64 + xc * 8);
    u64 hv[32];
#pragma unroll
    for (int s = 0; s < 16; ++s) {
      int p = s * 256 + tid;
      int row = p >> 7;
      int pc2 = p & 127;
      u64* gp = const_cast<u64*>(Hu) + row * 256 + pc2 * 2;
      hv[2 * s] = __hip_atomic_load(gp, __ATOMIC_RELAXED, __HIP_MEMORY_SCOPE_AGENT);
      hv[2 * s + 1] = __hip_atomic_load(gp + 1, __ATOMIC_RELAXED, __HIP_MEMORY_SCOPE_AGENT);
    }
    *reinterpret_cast<int4v*>(zs + xr * 2304 + ((xc * 16) ^ ((xr & 7) << 4))) = xv;
#pragma unroll
    for (int s = 0; s < 16; ++s) {
      int p = s * 256 + tid;
      int row = p >> 7;
      int pc2 = p & 127;
      int4v w;
      w.x = (int)(unsigned int)hv[2 * s];
      w.y = (int)(unsigned int)(hv[2 * s] >> 32);
      w.z = (int)(unsigned int)hv[2 * s + 1];
      w.w = (int)(unsigned int)(hv[2 * s + 1] >> 32);
      *reinterpret_cast<int4v*>(zs + row * 2304 + (((8 + pc2) * 16) ^ ((row & 7) << 4))) = w;
    }
    __syncthreads();

    // --- MFMA K-loop: 4 gates x 2 M-tiles, 9 K-tiles per wave ---
    float4v acc[4][2];
#pragma unroll
    for (int g = 0; g < 4; ++g) {
      acc[g][0] = (float4v){0.f, 0.f, 0.f, 0.f};
      acc[g][1] = (float4v){0.f, 0.f, 0.f, 0.f};
    }
#pragma unroll
    for (int j = 0; j < 9; ++j) {
      int bc = (wv * 9 + j) * 64 + lq * 16;
      short8 a0 = *reinterpret_cast<const short8*>(zs + lr * 2304 + (bc ^ ((lr & 7) << 4)));
      short8 a1 = *reinterpret_cast<const short8*>(zs + (16 + lr) * 2304 + (bc ^ ((lr & 7) << 4)));
#pragma unroll
      for (int g = 0; g < 4; ++g) {
        acc[g][0] = __builtin_amdgcn_mfma_f32_16x16x32_bf16(a0, bf[g][j], acc[g][0], 0, 0, 0);
        acc[g][1] = __builtin_amdgcn_mfma_f32_16x16x32_bf16(a1, bf[g][j], acc[g][1], 0, 0, 0);
      }
    }
    // transposed partial store: one float4 per (g,m) -> [col=lr][rows m*16+lq*4..+3]
#pragma unroll
    for (int g = 0; g < 4; ++g)
#pragma unroll
      for (int m = 0; m < 2; ++m)
        *reinterpret_cast<float4v*>(&pbuf2[wv][g][lr][m * 16 + lq * 4]) = acc[g][m];
    __syncthreads();

    // --- pointwise: reduce 4 wave-partials, gates -> c,h ---
    float lb[4][2];
    if (t == 1) {
#pragma unroll
      for (int g = 0; g < 4; ++g) {
        int j0 = g * 1024 + cg * 16 + pc;
        lb[g][0] = b1[j0];
        lb[g][1] = b1[j0 + 1];
      }
    } else {
#pragma unroll
      for (int g = 0; g < 4; ++g) { lb[g][0] = bias2[g][0]; lb[g][1] = bias2[g][1]; }
    }
    float ga0[4], ga1[4];
#pragma unroll
    for (int g = 0; g < 4; ++g) {
      ga0[g] = pbuf2[0][g][pc][pr] + pbuf2[1][g][pc][pr] + pbuf2[2][g][pc][pr] +
               pbuf2[3][g][pc][pr] + lb[g][0];
      ga1[g] = pbuf2[0][g][pc + 1][pr] + pbuf2[1][g][pc + 1][pr] + pbuf2[2][g][pc + 1][pr] +
               pbuf2[3][g][pc + 1][pr] + lb[g][1];
    }
    float i0 = sigm(ga0[0]), f0 = sigm(ga0[1]), gg0 = tanh_f(ga0[2]), o0 = sigm(ga0[3]);
    float i1 = sigm(ga1[0]), f1 = sigm(ga1[1]), gg1 = tanh_f(ga1[2]), o1 = sigm(ga1[3]);
    cst0 = f0 * cst0 + i0 * gg0;
    cst1 = f1 * cst1 + i1 * gg1;
    float h0 = o0 * tanh_f(cst0);
    float h1 = o1 * tanh_f(cst1);
    unsigned int packed = (unsigned int)f2bf(h0) | ((unsigned int)f2bf(h1) << 16);
    unsigned int* Hd = reinterpret_cast<unsigned int*>(Hbuf) + (t & 1) * 65536;
    __hip_atomic_store(Hd + (bg * 32 + pr) * 512 + cg * 8 + (tid & 7), packed,
                       __ATOMIC_RELAXED, __HIP_MEMORY_SCOPE_AGENT);
    // W_lin partial for this block's 16 columns (fp32 h, deterministic)
    float p = h0 * wl0 + h1 * wl1;
    p += __shfl_xor(p, 1);
    p += __shfl_xor(p, 2);
    p += __shfl_xor(p, 4);
    if ((tid & 7) == 0) outp[((size_t)t * 128 + bg * 32 + pr) * 64 + cg] = p;

    // --- publish: own h-stores retired at coherence point, then flag ---
    asm volatile("s_waitcnt vmcnt(0)" ::: "memory");
    __syncthreads();
    if (tid == 64)
      __hip_atomic_store(flags + bid, t, __ATOMIC_RELAXED, __HIP_MEMORY_SCOPE_AGENT);
  }
}

// ---- out[t][b] = b_lin + sum_cg outp[t][b][cg]; row 0 = INIT_OUT ----
__global__ void finalize(const float* __restrict__ outp, const float* __restrict__ b_lin,
                         float* __restrict__ out) {
  int row = blockIdx.x * 4 + (threadIdx.x >> 6);
  int lane = threadIdx.x & 63;
  if (row < 128) {
    if (lane == 0) out[row] = 1e-9f;
    return;
  }
  float v = outp[(size_t)row * 64 + lane];
  v += __shfl_down(v, 32);
  v += __shfl_down(v, 16);
  v += __shfl_down(v, 8);
  v += __shfl_down(v, 4);
  v += __shfl_down(v, 2);
  v += __shfl_down(v, 1);
  if (lane == 0) out[row] = v + b_lin[0];
}

extern "C" void kernel_launch(void* const* d_in, const int* in_sizes, int n_in,
                              void* d_out, int out_size, void* d_ws, size_t ws_size,
                              hipStream_t stream) {
  const float* x = (const float*)d_in[0];
  const float* W_ih = (const float*)d_in[1];
  const float* W_hh = (const float*)d_in[2];
  const float* b_ih = (const float*)d_in[3];
  const float* b_hh = (const float*)d_in[4];
  const float* W_lin = (const float*)d_in[5];
  const float* b_lin = (const float*)d_in[6];
  float* out = (float*)d_out;

  char* ws = (char*)d_ws;
  const size_t WS_WCAT = 0;                  // 4096*1152*2   = 9437184
  const size_t WS_XBF  = 9437184;            // 512*128*64*2  = 8388608
  const size_t WS_B1   = 17825792;           // 16384
  const size_t WS_B2   = 17842176;           // 16384
  const size_t WS_H    = 17858560;           // 2*128*1024*2  = 524288
  const size_t WS_OUTP = 18382848;           // 512*128*64*4  = 16777216
  const size_t WS_END  = 35160064;
  if (ws_size < WS_END + 64) return;         // insufficient scratch -> fail loudly

  unsigned short* Wcat = (unsigned short*)(ws + WS_WCAT);
  unsigned short* xbf = (unsigned short*)(ws + WS_XBF);
  float* b1 = (float*)(ws + WS_B1);
  float* b2 = (float*)(ws + WS_B2);
  unsigned short* Hbuf = (unsigned short*)(ws + WS_H);
  float* outp = (float*)(ws + WS_OUTP);
  int* flags = (int*)(ws + WS_OUTP);         // aliases outp row t=0 (never written/read)

  prep_w<<<18432, 256, 0, stream>>>(W_ih, W_hh, W_lin, b_ih, b_hh, b_lin, Wcat, b1, b2);
  prep_x<<<16384, 256, 0, stream>>>(x, xbf);
  initk<<<256, 256, 0, stream>>>(Hbuf, flags);
  lstm_rec<<<256, 256, 0, stream>>>(Wcat, xbf, b1, b2, W_lin, Hbuf, outp, flags);
  finalize<<<16384, 256, 0, stream>>>(outp, b_lin, out);
}

// Round 5
// 1987.093 us; speedup vs baseline: 4.3290x; 1.5153x over previous
//
#include <hip/hip_runtime.h>
#include <stdint.h>

// NpiLstm: T=512, B=128, H=1024, IN=64 (63 x-features + 1 feedback)
// Feedback folded into recurrent weights: W_hh' = W_hh + w_fb (x) W_lin.
// 256 persistent blocks; 8 independent groups of 32 blocks; group g handles
// batch rows [16g,16g+16), block owns h-cols [32mb,32mb+32).
// All h/flag exchange at the coherence point (sc0 sc1 = IC scope) — the
// R2-proven protocol. (R3/R4's XCD-local L2 exchange removed: its startup
// visibility probe is unsound — L2 eviction makes cross-XCD probes pass,
// then steady-state readers hit stale L2 lines -> 9.8e-3 corruption.)

typedef short short8 __attribute__((ext_vector_type(8)));
typedef float float4v __attribute__((ext_vector_type(4)));
typedef int int4v __attribute__((ext_vector_type(4)));
typedef int int2v __attribute__((ext_vector_type(2)));

#define KP 1152      // padded K: 63 x | 1 zero | 1024 h | 64 zero-pad
#define ZROW 2320    // zs row stride in bytes (2304 data + 16 pad -> bank spread)

__device__ __forceinline__ unsigned short f2bf(float f) {
  unsigned int u = __float_as_uint(f);
  u += 0x7fffu + ((u >> 16) & 1u);   // RNE
  return (unsigned short)(u >> 16);
}
__device__ __forceinline__ float sigm(float x) { return 1.0f / (1.0f + __expf(-x)); }
__device__ __forceinline__ float tanh_f(float x) {
  float ax = fabsf(x);
  float e = __expf(-2.0f * ax);
  float r = (1.0f - e) / (1.0f + e);
  return x < 0.0f ? -r : r;
}

// ---- build W_cat [4096][1152] bf16 and biases b1/b2 [4096] f32 ----
__global__ void prep_w(const float* __restrict__ W_ih, const float* __restrict__ W_hh,
                       const float* __restrict__ W_lin, const float* __restrict__ b_ih,
                       const float* __restrict__ b_hh, const float* __restrict__ b_lin,
                       unsigned short* __restrict__ Wcat, float* __restrict__ b1,
                       float* __restrict__ b2) {
  int idx = blockIdx.x * 256 + threadIdx.x;
  if (idx < 4096 * KP) {
    int j = idx / KP;
    int k = idx - j * KP;
    float v = 0.0f;
    if (k < 63) v = W_ih[j * 64 + k];
    else if (k >= 64 && k < 1088) {
      int kk = k - 64;
      v = W_hh[j * 1024 + kk] + W_ih[j * 64 + 63] * W_lin[kk];
    }
    Wcat[idx] = f2bf(v);
  }
  if (idx < 4096) {
    float wfb = W_ih[idx * 64 + 63];
    float base = b_ih[idx] + b_hh[idx];
    b1[idx] = base + 1e-9f * wfb;      // step 1: feedback value is INIT_OUT
    b2[idx] = base + b_lin[0] * wfb;   // steps >=2: folded b_lin feedback
  }
}

// ---- x -> bf16, padded to 64 channels ----
__global__ void prep_x(const float* __restrict__ x, unsigned short* __restrict__ xbf) {
  int idx = blockIdx.x * 256 + threadIdx.x;   // < 512*128*64 exactly
  int c = idx & 63;
  int bi = idx >> 6;
  unsigned short v = 0;
  if (c < 63) v = f2bf(x[bi * 63 + c]);
  xbf[idx] = v;
}

// ---- zero h0 buffers + flags ----
__global__ void initk(unsigned int* __restrict__ Hz, int* __restrict__ flags) {
  int idx = blockIdx.x * 256 + threadIdx.x;   // 0..65535
  Hz[idx] = 0u;
  Hz[idx + 65536] = 0u;
  if (idx < 1024) flags[idx] = 0;
}

// ---- persistent recurrent kernel: 256 blocks (1/CU), 256 threads ----
// group g = bid&7, member mb = bid>>3 in [0,32)
// wave wv: K-tiles [9wv, 9wv+9) of 36 (K-split, LDS partial reduce)
__global__ __launch_bounds__(256, 1) void lstm_rec(
    const unsigned short* __restrict__ Wcat, const unsigned short* __restrict__ xbf,
    const float* __restrict__ b1, const float* __restrict__ b2,
    const float* __restrict__ Wlin, unsigned short* __restrict__ Hbuf,
    float* __restrict__ outp, int* __restrict__ flags) {
  const int tid = threadIdx.x;
  const int bid = blockIdx.x;
  const int g = bid & 7;
  const int mb = bid >> 3;
  const int wv = tid >> 6;
  const int ln = tid & 63;
  const int lr = ln & 15;          // MFMA fragment row/col within 16
  const int lq = ln >> 4;          // k-quarter
  const int rp = wv * 2 + (ln >> 5);  // pointwise row-pair index 0..7
  const int c = ln & 31;              // pointwise col 0..31

  __shared__ __align__(16) char zs[16 * ZROW];          // Z: 16 rows x 1152 bf16
  __shared__ __align__(16) float pbuf[4][8][16][20];    // [wave][ntile][col][row+pad]

  // ---- zero zs ENTIRELY once (K-pad tiles 34/35 are read by MFMA but only
  //      bytes 0..2175 of each row are re-staged per step) ----
#pragma unroll
  for (int s = 0; s < 10; ++s) {
    int i = s * 256 + tid;
    if (i < 16 * ZROW / 16) {
      int4v z = {0, 0, 0, 0};
      *reinterpret_cast<int4v*>(zs + i * 16) = z;
    }
  }
  __syncthreads();   // zeroing must not race t=1 staging writes

  // ---- load B fragments (folded weights) into registers, once ----
  short8 bf[8][9];   // [ntile = gate*2 + colhalf][ktile within wave's 9]
#pragma unroll
  for (int n = 0; n < 8; ++n) {
    const unsigned short* wrow =
        Wcat + (size_t)((n >> 1) * 1024 + mb * 32 + (n & 1) * 16 + lr) * KP;
#pragma unroll
    for (int j = 0; j < 9; ++j)
      bf[n][j] = *reinterpret_cast<const short8*>(wrow + (wv * 9 + j) * 32 + lq * 8);
  }

  const int gcb = mb * 32 + c;     // this thread's h-column
  float bias2[4];
#pragma unroll
  for (int q = 0; q < 4; ++q) bias2[q] = b2[q * 1024 + gcb];
  const float wl = Wlin[gcb];
  float cs0 = 0.f, cs1 = 0.f;      // cell state (rows 2rp, 2rp+1) in registers

  for (int t = 1; t < 512; ++t) {
    const int tm1 = t - 1;
    // --- poll group flags (128 = 32 blocks x 4 waves), per-wave ---
    if (t > 1) {
      const int* fp = flags + g * 128 + ln * 2;
      int guard = 0;
      for (;;) {
        int2v ff;
        asm volatile("global_load_dwordx2 %0, %1, off sc0 sc1\n\ts_waitcnt vmcnt(0)"
                     : "=v"(ff) : "v"(fp) : "memory");
        if (__all((ff.x >= tm1) && (ff.y >= tm1))) break;
        if (++guard > (1 << 18)) break;   // hang-safety valve
      }
    }

    // --- stage Z = [x_t | 0 | h_{t-1} | pad] into LDS ---
    const unsigned short* hsrc =
        Hbuf + ((t - 1) & 1) * 131072 + (size_t)(g * 16) * 1024;
    const unsigned short* xsrc = xbf + (size_t)t * 8192 + (size_t)(g * 16) * 64;
    int4v tmp[8];
#pragma unroll
    for (int s = 0; s < 8; ++s) {
      int hc = s * 256 + tid;   // 0..2047 = 16 rows x 128 chunks
      const unsigned short* p = hsrc + (hc >> 7) * 1024 + (hc & 127) * 8;
      asm volatile("global_load_dwordx4 %0, %1, off sc0 sc1" : "=v"(tmp[s]) : "v"(p));
    }
    int4v xv;
    if (tid < 128)   // waves 0,1: 128 x-chunks (16 rows x 8)
      asm volatile("global_load_dwordx4 %0, %1, off"
                   : "=v"(xv) : "v"(xsrc + (tid >> 3) * 64 + (tid & 7) * 8));
    asm volatile("s_waitcnt vmcnt(0)" ::: "memory");
    __builtin_amdgcn_sched_barrier(0);
#pragma unroll
    for (int s = 0; s < 8; ++s) {
      int hc = s * 256 + tid;
      *reinterpret_cast<int4v*>(zs + (hc >> 7) * ZROW + 128 + (hc & 127) * 16) = tmp[s];
    }
    if (tid < 128)
      *reinterpret_cast<int4v*>(zs + (tid >> 3) * ZROW + (tid & 7) * 16) = xv;
    __syncthreads();

    // --- MFMA: 8 N-tiles (4 gates x 2 col-halves) x 9 K-tiles per wave ---
    float4v acc[8];
#pragma unroll
    for (int n = 0; n < 8; ++n) acc[n] = (float4v){0.f, 0.f, 0.f, 0.f};
#pragma unroll
    for (int j = 0; j < 9; ++j) {
      const short8 a = *reinterpret_cast<const short8*>(
          zs + lr * ZROW + (wv * 9 + j) * 64 + lq * 16);
#pragma unroll
      for (int n = 0; n < 8; ++n)
        acc[n] = __builtin_amdgcn_mfma_f32_16x16x32_bf16(a, bf[n][j], acc[n], 0, 0, 0);
    }
#pragma unroll
    for (int n = 0; n < 8; ++n)
      *reinterpret_cast<float4v*>(&pbuf[wv][n][lr][lq * 4]) = acc[n];
    __syncthreads();

    // --- pointwise: reduce 4 wave-partials, gates -> c,h (2 rows/thread) ---
    float ga0[4], ga1[4];
    const int nlo = c >> 4;
    const int cc = c & 15;
#pragma unroll
    for (int q = 0; q < 4; ++q) {
      float s0 = 0.f, s1 = 0.f;
#pragma unroll
      for (int w2 = 0; w2 < 4; ++w2) {
        const float* pp = &pbuf[w2][q * 2 + nlo][cc][2 * rp];
        s0 += pp[0];
        s1 += pp[1];
      }
      ga0[q] = s0;
      ga1[q] = s1;
    }
    float lb0 = bias2[0], lb1 = bias2[1], lb2 = bias2[2], lb3 = bias2[3];
    if (t == 1) {
      lb0 = b1[gcb];
      lb1 = b1[1024 + gcb];
      lb2 = b1[2048 + gcb];
      lb3 = b1[3072 + gcb];
    }
    float i0 = sigm(ga0[0] + lb0), f0 = sigm(ga0[1] + lb1);
    float G0 = tanh_f(ga0[2] + lb2), o0 = sigm(ga0[3] + lb3);
    float i1 = sigm(ga1[0] + lb0), f1 = sigm(ga1[1] + lb1);
    float G1 = tanh_f(ga1[2] + lb2), o1 = sigm(ga1[3] + lb3);
    cs0 = f0 * cs0 + i0 * G0;
    cs1 = f1 * cs1 + i1 * G1;
    float h0v = o0 * tanh_f(cs0);
    float h1v = o1 * tanh_f(cs1);

    // --- publish h (2 bf16 stores at coherence point), drain, per-wave flag ---
    unsigned short* Hd = Hbuf + (t & 1) * 131072;
    const int r0 = g * 16 + rp * 2;
    unsigned short* p0 = Hd + (size_t)r0 * 1024 + gcb;
    unsigned short* p1 = p0 + 1024;
    int hb0 = (int)f2bf(h0v), hb1 = (int)f2bf(h1v);
    asm volatile("global_store_short %0, %1, off sc0 sc1" :: "v"(p0), "v"(hb0) : "memory");
    asm volatile("global_store_short %0, %1, off sc0 sc1" :: "v"(p1), "v"(hb1) : "memory");
    asm volatile("s_waitcnt vmcnt(0)" ::: "memory");
    if (ln == 0) {
      int* fp2 = flags + g * 128 + mb * 4 + wv;
      asm volatile("global_store_dword %0, %1, off sc0 sc1" :: "v"(fp2), "v"(t) : "memory");
    }

    // --- W_lin partial for this block's 32 cols (after flag; not on chain) ---
    float pa = h0v * wl, pb = h1v * wl;
    pa += __shfl_xor(pa, 1); pb += __shfl_xor(pb, 1);
    pa += __shfl_xor(pa, 2); pb += __shfl_xor(pb, 2);
    pa += __shfl_xor(pa, 4); pb += __shfl_xor(pb, 4);
    pa += __shfl_xor(pa, 8); pb += __shfl_xor(pb, 8);
    pa += __shfl_xor(pa, 16); pb += __shfl_xor(pb, 16);
    if (c == 0) {
      outp[(size_t)(t * 128 + r0) * 32 + mb] = pa;
      outp[(size_t)(t * 128 + r0 + 1) * 32 + mb] = pb;
    }
  }
}

// ---- out[t][b] = b_lin + sum_mb outp[t][b][mb]; rows t=0 -> INIT_OUT ----
__global__ void finalize(const float* __restrict__ outp, const float* __restrict__ b_lin,
                         float* __restrict__ out) {
  int tid = threadIdx.x;
  int ln = tid & 63;
  int wv = tid >> 6;
  int half = ln >> 5;
  int lane = ln & 31;
  int row = blockIdx.x * 8 + wv * 2 + half;   // < 65536
  float v = outp[(size_t)row * 32 + lane];
  v += __shfl_xor(v, 1);
  v += __shfl_xor(v, 2);
  v += __shfl_xor(v, 4);
  v += __shfl_xor(v, 8);
  v += __shfl_xor(v, 16);
  if (lane == 0) out[row] = (row < 128) ? 1e-9f : (v + b_lin[0]);
}

extern "C" void kernel_launch(void* const* d_in, const int* in_sizes, int n_in,
                              void* d_out, int out_size, void* d_ws, size_t ws_size,
                              hipStream_t stream) {
  const float* x = (const float*)d_in[0];
  const float* W_ih = (const float*)d_in[1];
  const float* W_hh = (const float*)d_in[2];
  const float* b_ih = (const float*)d_in[3];
  const float* b_hh = (const float*)d_in[4];
  const float* W_lin = (const float*)d_in[5];
  const float* b_lin = (const float*)d_in[6];
  float* out = (float*)d_out;

  char* ws = (char*)d_ws;
  const size_t WS_WCAT = 0;                  // 4096*1152*2   = 9437184
  const size_t WS_XBF  = 9437184;            // 512*128*64*2  = 8388608
  const size_t WS_B1   = 17825792;           // 16384
  const size_t WS_B2   = 17842176;           // 16384
  const size_t WS_H    = 17858560;           // 2*128*1024*2  = 524288
  const size_t WS_OUTP = 18382848;           // 512*128*32*4  = 8388608
  const size_t WS_FLAG = 26771456;           // 4096
  if (ws_size < WS_FLAG + 4096) return;      // insufficient scratch -> fail loudly

  unsigned short* Wcat = (unsigned short*)(ws + WS_WCAT);
  unsigned short* xbf = (unsigned short*)(ws + WS_XBF);
  float* b1 = (float*)(ws + WS_B1);
  float* b2 = (float*)(ws + WS_B2);
  unsigned short* Hbuf = (unsigned short*)(ws + WS_H);
  float* outp = (float*)(ws + WS_OUTP);
  int* flags = (int*)(ws + WS_FLAG);

  prep_w<<<18432, 256, 0, stream>>>(W_ih, W_hh, W_lin, b_ih, b_hh, b_lin, Wcat, b1, b2);
  prep_x<<<16384, 256, 0, stream>>>(x, xbf);
  initk<<<256, 256, 0, stream>>>((unsigned int*)Hbuf, flags);
  lstm_rec<<<256, 256, 0, stream>>>(Wcat, xbf, b1, b2, W_lin, Hbuf, outp, flags);
  finalize<<<8192, 256, 0, stream>>>(outp, b_lin, out);
}